// Round 3
// baseline (157.982 us; speedup 1.0000x reference)
//
#include <hip/hip_runtime.h>

#define T_SEQ 2048
#define DHEAD 128
#define NBH 16
#define SCALE 0.08838834764831845f

typedef unsigned short u16;
typedef u16 u16x4 __attribute__((ext_vector_type(4)));
typedef u16 u16x8 __attribute__((ext_vector_type(8)));
typedef __bf16 bf16x8 __attribute__((ext_vector_type(8)));
typedef float f32x4 __attribute__((ext_vector_type(4)));

__device__ __forceinline__ u16 f2bfu(float x) {
  union { float f; unsigned u; } c; c.f = x;
  unsigned u = c.u;
  u = u + 0x7FFFu + ((u >> 16) & 1u);   // RNE
  return (u16)(u >> 16);
}

__device__ __forceinline__ bf16x8 ldsFrag(const u16* p) {
  u16x8 t = *(const u16x8*)p;
  return __builtin_bit_cast(bf16x8, t);
}

__device__ __forceinline__ void gld_lds16(const void* g, void* l) {
  __builtin_amdgcn_global_load_lds(
      (__attribute__((address_space(1))) const unsigned int*)g,
      (__attribute__((address_space(3))) unsigned int*)l, 16, 0, 0);
}

// ---------------------------------------------------------------------------
// Gate scan: fc=cumsum(logsigmoid(f)); a=i-fc; c=cummax(a); nfl=exp(-(c+fc)).
// ---------------------------------------------------------------------------
__global__ __launch_bounds__(256) void gate_scan_kernel(
    const float* __restrict__ ig, const float* __restrict__ fg,
    float* __restrict__ a_out, float* __restrict__ c_out,
    float* __restrict__ nfl_out)
{
  const int bh  = blockIdx.x;
  const int tid = threadIdx.x;
  const int base = bh * T_SEQ + tid * 8;
  __shared__ float sbuf[256];

  float lf[8];
  float run = 0.f;
#pragma unroll
  for (int j = 0; j < 8; ++j) {
    float x  = fg[base + j];
    float ls = fminf(x, 0.f) - log1pf(expf(-fabsf(x)));
    run += ls; lf[j] = run;
  }
  sbuf[tid] = run; __syncthreads();
  for (int off = 1; off < 256; off <<= 1) {
    float t = (tid >= off) ? sbuf[tid - off] : 0.f;
    __syncthreads();
    sbuf[tid] += t;
    __syncthreads();
  }
  const float excl = (tid > 0) ? sbuf[tid - 1] : 0.f;
  __syncthreads();

  float fc[8], cm[8];
  float runm = -INFINITY;
#pragma unroll
  for (int j = 0; j < 8; ++j) {
    fc[j] = excl + lf[j];
    float av = ig[base + j] - fc[j];
    a_out[base + j] = av;
    runm = fmaxf(runm, av);
    cm[j] = runm;
  }
  sbuf[tid] = runm; __syncthreads();
  for (int off = 1; off < 256; off <<= 1) {
    float t = (tid >= off) ? sbuf[tid - off] : -INFINITY;
    __syncthreads();
    sbuf[tid] = fmaxf(sbuf[tid], t);
    __syncthreads();
  }
  const float exclm = (tid > 0) ? sbuf[tid - 1] : -INFINITY;
#pragma unroll
  for (int j = 0; j < 8; ++j) {
    float c = fmaxf(exclm, cm[j]);
    c_out[base + j]   = c;
    nfl_out[base + j] = expf(-(c + fc[j]));
  }
}

// ---------------------------------------------------------------------------
// Pre-pass: K fp32 -> bf16 (same layout).
// ---------------------------------------------------------------------------
__global__ __launch_bounds__(256) void cvt_k_kernel(
    const float* __restrict__ src, u16* __restrict__ dst)
{
  const int i = (blockIdx.x * 256 + threadIdx.x) * 4;
  const float4 x = *(const float4*)(src + i);
  u16x4 p; p[0] = f2bfu(x.x); p[1] = f2bfu(x.y); p[2] = f2bfu(x.z); p[3] = f2bfu(x.w);
  *(u16x4*)(dst + i) = p;
}

// ---------------------------------------------------------------------------
// Pre-pass: V fp32 [bh][key][n] -> bf16 transposed Vt [bh][n][key].
// ---------------------------------------------------------------------------
__global__ __launch_bounds__(256) void cvt_vt_kernel(
    const float* __restrict__ v, u16* __restrict__ vt)
{
  const int bh = blockIdx.y, kt = blockIdx.x, tid = threadIdx.x;
  __shared__ __align__(16) u16 L[128 * 72];
  const int n0 = (tid & 31) * 4, k0 = (tid >> 5) * 8;
  const float* vp = v + ((size_t)bh * T_SEQ + kt * 64 + k0) * DHEAD + n0;
  u16 tv[4][8];
#pragma unroll
  for (int rr = 0; rr < 8; ++rr) {
    const float4 x = *(const float4*)(vp + rr * DHEAD);
    tv[0][rr] = f2bfu(x.x); tv[1][rr] = f2bfu(x.y);
    tv[2][rr] = f2bfu(x.z); tv[3][rr] = f2bfu(x.w);
  }
#pragma unroll
  for (int j = 0; j < 4; ++j) {
    u16x8 p;
#pragma unroll
    for (int rr = 0; rr < 8; ++rr) p[rr] = tv[j][rr];
    *(u16x8*)(&L[(n0 + j) * 72 + k0]) = p;
  }
  __syncthreads();
  const int row = tid >> 1, s0 = (tid & 1) * 32;
  u16* op = vt + ((size_t)bh * DHEAD + row) * T_SEQ + kt * 64 + s0;
#pragma unroll
  for (int i = 0; i < 4; ++i)
    *(u16x8*)(op + i * 8) = *(const u16x8*)(&L[row * 72 + s0 + i * 8]);
}

// ---------------------------------------------------------------------------
// Main flash mLSTM.  256 blocks x 512 threads.  Two independent 4-wave groups
// per block process complementary q-tiles (31-p and p) of the SAME head ->
// uniform 33 tile-computes per block, 1 block/CU (LDS 144KB), deterministic
// balance.  Double-buffered async staging per group; exp factorization:
// P' = S*scale*exp(a[s]-cmax), row factor exp(cmax-c[t]) applied in epilogue.
// ---------------------------------------------------------------------------
template <bool FAST>
__global__ __launch_bounds__(512, 1) void mlstm_fwd_kernel(
    const float* __restrict__ qg, const float* __restrict__ kg,
    const float* __restrict__ vg,
    const u16* __restrict__ kbf, const u16* __restrict__ vtbf,
    const float* __restrict__ ag, const float* __restrict__ cg,
    const float* __restrict__ nflg, float* __restrict__ out)
{
  const int bx = (int)blockIdx.x;
  const int bh = bx & 15, p = bx >> 4;           // head, pair index
  const int tid = (int)threadIdx.x;
  const int grp = tid >> 8;                      // 0 or 1
  const int gt  = tid & 255;                     // id within group
  const int wave = gt >> 6, lane = gt & 63;
  const int quad = lane >> 4, l16 = lane & 15;
  const int w8   = tid >> 6;                     // wave id 0..7

  const int qt    = grp ? p : (31 - p);          // this group's q-tile
  const int qtMax = 31 - p;                      // loop length driver

  __shared__ __align__(16) u16 KB[2][2][64 * 128];  // [group][buf]
  __shared__ __align__(16) u16 VB[2][2][128 * 64];
  __shared__ __align__(16) u16 Pl[8][16 * 64];      // swizzled, per wave

  const size_t hoff = (size_t)bh * T_SEQ * DHEAD;
  const int goff = bh * T_SEQ;
  const int qrowA = qt * 64 + wave * 16 + l16;
  const int trow0 = qt * 64 + wave * 16 + quad * 4;

  // Q strip -> A-frags
  bf16x8 qf[4];
  {
    const float* qp = qg + hoff + (size_t)qrowA * DHEAD + quad * 8;
#pragma unroll
    for (int kc = 0; kc < 4; ++kc) {
      const float4 x0 = *(const float4*)(qp + kc * 32);
      const float4 x1 = *(const float4*)(qp + kc * 32 + 4);
      u16x8 t;
      t[0] = f2bfu(x0.x); t[1] = f2bfu(x0.y); t[2] = f2bfu(x0.z); t[3] = f2bfu(x0.w);
      t[4] = f2bfu(x1.x); t[5] = f2bfu(x1.y); t[6] = f2bfu(x1.z); t[7] = f2bfu(x1.w);
      qf[kc] = __builtin_bit_cast(bf16x8, t);
    }
  }
  const float cmax = cg[goff + qt * 64 + 63];    // max c in tile (cummax)

  f32x4 oa[8];
#pragma unroll
  for (int nv = 0; nv < 8; ++nv) oa[nv] = (f32x4){0.f, 0.f, 0.f, 0.f};
  float rs[4] = {0.f, 0.f, 0.f, 0.f};

  // fallback staging registers
  float4 kr[8], vr[8];
  const int fb_keyb = gt >> 4;
  const int fb_db   = (gt & 15) ^ ((gt >> 4) & 7);
  const int fb_n0 = (gt & 31) * 4, fb_k0 = (gt >> 5) * 8;

  auto stage_issue = [&](int kt, int b) {
    if (FAST) {
      const u16* ks = kbf + ((size_t)goff + kt * 64) * DHEAD;
      const u16* vs = vtbf + (size_t)bh * DHEAD * T_SEQ + kt * 64;
#pragma unroll
      for (int j = 0; j < 4; ++j) {
        const int B = (wave * 4 + j) * 64 + lane;
        {
          const int key = B >> 4;
          const int db = (B & 15) ^ (key & 7);
          gld_lds16(ks + (size_t)key * DHEAD + db * 8, &KB[grp][b][(wave * 4 + j) * 512]);
        }
        {
          const int n = B >> 3;
          const int kb = (B & 7) ^ (n & 7);
          gld_lds16(vs + (size_t)n * T_SEQ + kb * 8, &VB[grp][b][(wave * 4 + j) * 512]);
        }
      }
    } else {
      const float* kp = kg + hoff + (size_t)(kt * 64) * DHEAD;
      const float* vp = vg + hoff + (size_t)(kt * 64 + fb_k0) * DHEAD + fb_n0;
#pragma unroll
      for (int jb = 0; jb < 4; ++jb) {
        const int key = fb_keyb + 16 * jb;
        kr[2 * jb]     = *(const float4*)(kp + (size_t)key * DHEAD + fb_db * 8);
        kr[2 * jb + 1] = *(const float4*)(kp + (size_t)key * DHEAD + fb_db * 8 + 4);
      }
#pragma unroll
      for (int rr = 0; rr < 8; ++rr) vr[rr] = *(const float4*)(vp + rr * DHEAD);
    }
  };
  auto stage_commit = [&](int b) {
    if (!FAST) {
#pragma unroll
      for (int jb = 0; jb < 4; ++jb) {
        const int key = fb_keyb + 16 * jb;
        u16x8 pk;
        pk[0] = f2bfu(kr[2*jb].x);   pk[1] = f2bfu(kr[2*jb].y);
        pk[2] = f2bfu(kr[2*jb].z);   pk[3] = f2bfu(kr[2*jb].w);
        pk[4] = f2bfu(kr[2*jb+1].x); pk[5] = f2bfu(kr[2*jb+1].y);
        pk[6] = f2bfu(kr[2*jb+1].z); pk[7] = f2bfu(kr[2*jb+1].w);
        *(u16x8*)(&KB[grp][b][(key * 16 + (gt & 15)) * 8]) = pk;
      }
      u16 tv[4][8];
#pragma unroll
      for (int rr = 0; rr < 8; ++rr) {
        tv[0][rr] = f2bfu(vr[rr].x); tv[1][rr] = f2bfu(vr[rr].y);
        tv[2][rr] = f2bfu(vr[rr].z); tv[3][rr] = f2bfu(vr[rr].w);
      }
      const int kb = fb_k0 >> 3;
#pragma unroll
      for (int j = 0; j < 4; ++j) {
        const int n = fb_n0 + j;
        u16x8 pk;
#pragma unroll
        for (int rr = 0; rr < 8; ++rr) pk[rr] = tv[j][rr];
        *(u16x8*)(&VB[grp][b][(n * 8 + (kb ^ (n & 7))) * 8]) = pk;
      }
    }
  };

  stage_issue(0, 0);
  stage_commit(0);
  __syncthreads();

  for (int kt = 0; kt <= qtMax; ++kt) {
    const int b = kt & 1;
    const bool act = (kt <= qt);
    if (act && kt < qt) stage_issue(kt + 1, b ^ 1);

    if (act) {
      float an[4];
#pragma unroll
      for (int nc = 0; nc < 4; ++nc) an[nc] = ag[goff + kt * 64 + nc * 16 + l16];

      const bool diag = (kt == qt);
#pragma unroll
      for (int nc = 0; nc < 4; ++nc) {
        f32x4 s = (f32x4){0.f, 0.f, 0.f, 0.f};
        const int key = nc * 16 + l16;
#pragma unroll
        for (int kc = 0; kc < 4; ++kc) {
          const int db = (kc * 4 + quad) ^ (l16 & 7);
          const bf16x8 bk = ldsFrag(&KB[grp][b][(key * 16 + db) * 8]);
          s = __builtin_amdgcn_mfma_f32_16x16x32_bf16(qf[kc], bk, s, 0, 0, 0);
        }
        const float es = SCALE * __expf(an[nc] - cmax);   // <= SCALE
        const int scol = nc * 16 + l16;
#pragma unroll
        for (int r = 0; r < 4; ++r) {
          float pv = s[r] * es;
          if (diag && (kt * 64 + scol > trow0 + r)) pv = 0.f;
          rs[r] += pv;
          const int m = quad * 4 + r;
          Pl[w8][m * 64 + ((((scol >> 3) ^ (m & 7)) << 3) | (scol & 7))] = f2bfu(pv);
        }
      }
#pragma unroll
      for (int kk = 0; kk < 2; ++kk) {
        const bf16x8 pa = ldsFrag(&Pl[w8][l16 * 64 + (((kk * 4 + quad) ^ (l16 & 7)) << 3)]);
#pragma unroll
        for (int nv = 0; nv < 8; ++nv) {
          const int n = nv * 16 + l16;
          const int kb = (kk * 4 + quad) ^ (l16 & 7);
          const bf16x8 bv = ldsFrag(&VB[grp][b][(n * 8 + kb) * 8]);
          oa[nv] = __builtin_amdgcn_mfma_f32_16x16x32_bf16(pa, bv, oa[nv], 0, 0, 0);
        }
      }
    }
    if (act && kt < qt) stage_commit(b ^ 1);
    __syncthreads();
  }

  // ---- epilogue: rowsum reduce, apply row factor exp(cmax - c[t]) ----
#pragma unroll
  for (int r = 0; r < 4; ++r) {
    float x = rs[r];
#pragma unroll
    for (int off = 1; off < 16; off <<= 1) x += __shfl_xor(x, off, 64);
    rs[r] = x;
  }
  float inv[4];
#pragma unroll
  for (int r = 0; r < 4; ++r) {
    const float crv  = cg[goff + trow0 + r];
    const float erow = __expf(cmax - crv);
    const float nf   = nflg[goff + trow0 + r];
    inv[r] = erow / fmaxf(fabsf(rs[r] * erow), nf);
  }
  float* op = out + hoff;
#pragma unroll
  for (int nv = 0; nv < 8; ++nv) {
#pragma unroll
    for (int r = 0; r < 4; ++r) {
      op[(size_t)(trow0 + r) * DHEAD + nv * 16 + l16] = oa[nv][r] * inv[r];
    }
  }
}

// ---------------------------------------------------------------------------
extern "C" void kernel_launch(void* const* d_in, const int* in_sizes, int n_in,
                              void* d_out, int out_size, void* d_ws, size_t ws_size,
                              hipStream_t stream) {
  const float* q  = (const float*)d_in[0];
  const float* k  = (const float*)d_in[1];
  const float* v  = (const float*)d_in[2];
  const float* ig = (const float*)d_in[3];
  const float* fg = (const float*)d_in[4];

  const size_t gate_bytes = (size_t)3 * NBH * T_SEQ * sizeof(float);
  const size_t kv_elems   = (size_t)NBH * T_SEQ * DHEAD;
  const bool fast = ws_size >= gate_bytes + 2 * kv_elems * sizeof(u16);

  float* a_ws   = (float*)d_ws;
  float* c_ws   = a_ws + NBH * T_SEQ;
  float* nfl_ws = c_ws + NBH * T_SEQ;
  u16* kbf  = (u16*)((char*)d_ws + gate_bytes);
  u16* vtbf = kbf + kv_elems;

  gate_scan_kernel<<<dim3(NBH), dim3(256), 0, stream>>>(ig, fg, a_ws, c_ws, nfl_ws);
  if (fast) {
    cvt_k_kernel<<<dim3((unsigned)(kv_elems / 1024)), dim3(256), 0, stream>>>(k, kbf);
    cvt_vt_kernel<<<dim3(T_SEQ / 64, NBH), dim3(256), 0, stream>>>(v, vtbf);
    mlstm_fwd_kernel<true><<<dim3(256), dim3(512), 0, stream>>>(
        q, k, v, kbf, vtbf, a_ws, c_ws, nfl_ws, (float*)d_out);
  } else {
    mlstm_fwd_kernel<false><<<dim3(256), dim3(512), 0, stream>>>(
        q, k, v, kbf, vtbf, a_ws, c_ws, nfl_ws, (float*)d_out);
  }
}

// Round 4
// 150.652 us; speedup vs baseline: 1.0487x; 1.0487x over previous
//
#include <hip/hip_runtime.h>

#define T_SEQ 2048
#define DHEAD 128
#define NBH 16
#define SCALE 0.08838834764831845f

typedef unsigned short u16;
typedef u16 u16x4 __attribute__((ext_vector_type(4)));
typedef u16 u16x8 __attribute__((ext_vector_type(8)));
typedef __bf16 bf16x8 __attribute__((ext_vector_type(8)));
typedef float f32x16 __attribute__((ext_vector_type(16)));

__device__ __forceinline__ u16 f2bfu(float x) {
  union { float f; unsigned u; } c; c.f = x;
  unsigned u = c.u;
  u = u + 0x7FFFu + ((u >> 16) & 1u);   // RNE
  return (u16)(u >> 16);
}

__device__ __forceinline__ bf16x8 ldsFrag(const u16* p) {
  u16x8 t = *(const u16x8*)p;
  return __builtin_bit_cast(bf16x8, t);
}

__device__ __forceinline__ void gld_lds16(const void* g, void* l) {
  __builtin_amdgcn_global_load_lds(
      (__attribute__((address_space(1))) const unsigned int*)g,
      (__attribute__((address_space(3))) unsigned int*)l, 16, 0, 0);
}

// ---------------------------------------------------------------------------
// Gate scan: fc=cumsum(logsigmoid(f)); a=i-fc; c=cummax(a).
// ---------------------------------------------------------------------------
__global__ __launch_bounds__(256) void gate_scan_kernel(
    const float* __restrict__ ig, const float* __restrict__ fg,
    float* __restrict__ a_out, float* __restrict__ c_out,
    float* __restrict__ fc_out)
{
  const int bh  = blockIdx.x;
  const int tid = threadIdx.x;
  const int base = bh * T_SEQ + tid * 8;
  __shared__ float sbuf[256];

  float lf[8];
  float run = 0.f;
#pragma unroll
  for (int j = 0; j < 8; ++j) {
    float x  = fg[base + j];
    float ls = fminf(x, 0.f) - log1pf(expf(-fabsf(x)));
    run += ls; lf[j] = run;
  }
  sbuf[tid] = run; __syncthreads();
  for (int off = 1; off < 256; off <<= 1) {
    float t = (tid >= off) ? sbuf[tid - off] : 0.f;
    __syncthreads();
    sbuf[tid] += t;
    __syncthreads();
  }
  const float excl = (tid > 0) ? sbuf[tid - 1] : 0.f;
  __syncthreads();

  float fc[8], cm[8];
  float runm = -INFINITY;
#pragma unroll
  for (int j = 0; j < 8; ++j) {
    fc[j] = excl + lf[j];
    fc_out[base + j] = fc[j];
    float av = ig[base + j] - fc[j];
    a_out[base + j] = av;
    runm = fmaxf(runm, av);
    cm[j] = runm;
  }
  sbuf[tid] = runm; __syncthreads();
  for (int off = 1; off < 256; off <<= 1) {
    float t = (tid >= off) ? sbuf[tid - off] : -INFINITY;
    __syncthreads();
    sbuf[tid] = fmaxf(sbuf[tid], t);
    __syncthreads();
  }
  const float exclm = (tid > 0) ? sbuf[tid - 1] : -INFINITY;
#pragma unroll
  for (int j = 0; j < 8; ++j) {
    c_out[base + j] = fmaxf(exclm, cm[j]);
  }
}

// ---------------------------------------------------------------------------
// Pre-pass: K fp32 -> bf16 (same layout).
// ---------------------------------------------------------------------------
__global__ __launch_bounds__(256) void cvt_k_kernel(
    const float* __restrict__ src, u16* __restrict__ dst)
{
  const int i = (blockIdx.x * 256 + threadIdx.x) * 4;
  const float4 x = *(const float4*)(src + i);
  u16x4 p; p[0] = f2bfu(x.x); p[1] = f2bfu(x.y); p[2] = f2bfu(x.z); p[3] = f2bfu(x.w);
  *(u16x4*)(dst + i) = p;
}

// ---------------------------------------------------------------------------
// Pre-pass: V fp32 [bh][key][n] -> bf16 transposed Vt [bh][n][key].
// ---------------------------------------------------------------------------
__global__ __launch_bounds__(256) void cvt_vt_kernel(
    const float* __restrict__ v, u16* __restrict__ vt)
{
  const int bh = blockIdx.y, kt = blockIdx.x, tid = threadIdx.x;
  __shared__ __align__(16) u16 L[128 * 72];
  const int n0 = (tid & 31) * 4, k0 = (tid >> 5) * 8;
  const float* vp = v + ((size_t)bh * T_SEQ + kt * 64 + k0) * DHEAD + n0;
  u16 tv[4][8];
#pragma unroll
  for (int rr = 0; rr < 8; ++rr) {
    const float4 x = *(const float4*)(vp + rr * DHEAD);
    tv[0][rr] = f2bfu(x.x); tv[1][rr] = f2bfu(x.y);
    tv[2][rr] = f2bfu(x.z); tv[3][rr] = f2bfu(x.w);
  }
#pragma unroll
  for (int j = 0; j < 4; ++j) {
    u16x8 p;
#pragma unroll
    for (int rr = 0; rr < 8; ++rr) p[rr] = tv[j][rr];
    *(u16x8*)(&L[(n0 + j) * 72 + k0]) = p;
  }
  __syncthreads();
  const int row = tid >> 1, s0 = (tid & 1) * 32;
  u16* op = vt + ((size_t)bh * DHEAD + row) * T_SEQ + kt * 64 + s0;
#pragma unroll
  for (int i = 0; i < 4; ++i)
    *(u16x8*)(op + i * 8) = *(const u16x8*)(&L[row * 72 + s0 + i * 8]);
}

// ---------------------------------------------------------------------------
// Main flash mLSTM.  256 blocks x 512 thr (8 waves).  32x32x16 MFMA, H=32.
// Pair (qtA=31-p, qtB=p); per q-tile 4 waves = 2 row-strips x 2 key-halves.
// Shared dbuf K/V staging (64KB) + per-wave P buffers (16KB) = 80KB LDS.
// Key-half partial O/rowsum combined through LDS (reusing staging space).
// Layouts (32x32x16 bf16): A: m=lane&31, k=(lane>>5)*8+j; B: n=lane&31,
// k=(lane>>5)*8+j; C/D: col=lane&31, row=(reg&3)+8*(reg>>2)+4*(lane>>5).
// ---------------------------------------------------------------------------
template <bool FAST>
__global__ __launch_bounds__(512, 2) void mlstm_fwd_kernel(
    const float* __restrict__ qg, const float* __restrict__ kg,
    const float* __restrict__ vg,
    const u16* __restrict__ kbf, const u16* __restrict__ vtbf,
    const float* __restrict__ ag, const float* __restrict__ cg,
    const float* __restrict__ fcg, float* __restrict__ out)
{
  const int bx = (int)blockIdx.x;
  const int bh = bx & 15, p = bx >> 4;
  const int tid = (int)threadIdx.x;
  const int w8 = tid >> 6, lane = tid & 63;
  const int hh = lane >> 5, l32 = lane & 31;

  const int qsel  = w8 >> 2;          // 0: tile A (31-p), 1: tile B (p)
  const int half  = (w8 >> 1) & 1;    // key half within 64-key super-tile
  const int strip = w8 & 1;           // 32-row strip within 64-row q-tile
  const int qt    = qsel ? p : (31 - p);
  const int nST   = 32 - p;
  const int diagST = qsel ? p : (31 - p);
  const int qrow0 = qt * 64 + strip * 32;

  __shared__ __align__(16) unsigned char SM[81920];
  // buf b: K @ b*32768 (64 keys x 128 dims bf16), V @ b*32768+16384 (128 n x 64 keys)
  // Pl @ 65536 + w8*2048 (32x32 bf16, xor-swizzled)
  u16* Plw = (u16*)(SM + 65536 + w8 * 2048);

  const size_t hoff = (size_t)bh * T_SEQ * DHEAD;
  const int goff = bh * T_SEQ;

  // Q strip -> 8 A-frags
  bf16x8 qf[8];
  {
    const float* qp = qg + hoff + (size_t)(qrow0 + l32) * DHEAD + hh * 8;
#pragma unroll
    for (int ks_ = 0; ks_ < 8; ++ks_) {
      const float4 x0 = *(const float4*)(qp + ks_ * 16);
      const float4 x1 = *(const float4*)(qp + ks_ * 16 + 4);
      u16x8 t;
      t[0] = f2bfu(x0.x); t[1] = f2bfu(x0.y); t[2] = f2bfu(x0.z); t[3] = f2bfu(x0.w);
      t[4] = f2bfu(x1.x); t[5] = f2bfu(x1.y); t[6] = f2bfu(x1.z); t[7] = f2bfu(x1.w);
      qf[ks_] = __builtin_bit_cast(bf16x8, t);
    }
  }
  const float cmax = cg[goff + qt * 64 + 63];

  f32x16 oa[4];
#pragma unroll
  for (int nt = 0; nt < 4; ++nt)
#pragma unroll
    for (int r = 0; r < 16; ++r) oa[nt][r] = 0.f;
  float rs[16];
#pragma unroll
  for (int r = 0; r < 16; ++r) rs[r] = 0.f;

  float kr[2][8], vr[2][8];   // fallback staging regs

  auto stage_issue = [&](int st, int b) {
    if (FAST) {
      const u16* ks = kbf + ((size_t)goff + st * 64) * DHEAD;
      const u16* vs = vtbf + (size_t)bh * DHEAD * T_SEQ + st * 64;
#pragma unroll
      for (int j = 0; j < 2; ++j) {
        const int B = (w8 * 2 + j) * 64 + lane;
        {
          const int key = B >> 4;
          const int db = (B & 15) ^ (key & 7);
          gld_lds16(ks + (size_t)key * DHEAD + db * 8,
                    (u16*)(SM + b * 32768) + (w8 * 2 + j) * 512);
        }
        {
          const int n = B >> 3;
          const int kb = (B & 7) ^ (n & 7);
          gld_lds16(vs + (size_t)n * T_SEQ + kb * 8,
                    (u16*)(SM + b * 32768 + 16384) + (w8 * 2 + j) * 512);
        }
      }
    } else {
      const float* kp = kg + hoff + (size_t)(st * 64) * DHEAD;
      const float* vp = vg + hoff + (size_t)(st * 64) * DHEAD;
#pragma unroll
      for (int j = 0; j < 2; ++j) {
        const int B = (w8 * 2 + j) * 64 + lane;
        const int key = B >> 4;
        const int db = (B & 15) ^ (key & 7);
        const float4 x0 = *(const float4*)(kp + (size_t)key * DHEAD + db * 8);
        const float4 x1 = *(const float4*)(kp + (size_t)key * DHEAD + db * 8 + 4);
        kr[j][0] = x0.x; kr[j][1] = x0.y; kr[j][2] = x0.z; kr[j][3] = x0.w;
        kr[j][4] = x1.x; kr[j][5] = x1.y; kr[j][6] = x1.z; kr[j][7] = x1.w;
        const int n = B >> 3;
        const int kb = (B & 7) ^ (n & 7);
#pragma unroll
        for (int rr = 0; rr < 8; ++rr)
          vr[j][rr] = vp[(size_t)(kb * 8 + rr) * DHEAD + n];
      }
    }
  };
  auto stage_commit = [&](int b) {
    if (!FAST) {
#pragma unroll
      for (int j = 0; j < 2; ++j) {
        u16x8 pk, pv;
#pragma unroll
        for (int rr = 0; rr < 8; ++rr) { pk[rr] = f2bfu(kr[j][rr]); pv[rr] = f2bfu(vr[j][rr]); }
        *(u16x8*)((u16*)(SM + b * 32768) + (w8 * 2 + j) * 512 + lane * 8) = pk;
        *(u16x8*)((u16*)(SM + b * 32768 + 16384) + (w8 * 2 + j) * 512 + lane * 8) = pv;
      }
    }
  };

  stage_issue(0, 0);
  stage_commit(0);
  __syncthreads();

  const int plc = (lane >> 3) & 3, pl7 = lane & 7;

  for (int st = 0; st < nST; ++st) {
    const int b = st & 1;
    if (st + 1 < nST) stage_issue(st + 1, b ^ 1);

    const bool act = (qsel == 0) || (st <= p);
    if (act) {
      const int keyl = half * 32 + l32;
      const int keyg = st * 64 + keyl;
      const float av = ag[goff + keyg];
      const u16* Kb_ = (const u16*)(SM + b * 32768);
      const u16* Vb_ = (const u16*)(SM + b * 32768 + 16384);

      f32x16 s;
#pragma unroll
      for (int r = 0; r < 16; ++r) s[r] = 0.f;
#pragma unroll
      for (int ks_ = 0; ks_ < 8; ++ks_) {
        const int db = 2 * ks_ + hh;
        const bf16x8 bk = ldsFrag(Kb_ + keyl * 128 + ((db ^ (keyl & 7)) * 8));
        s = __builtin_amdgcn_mfma_f32_32x32x16_bf16(qf[ks_], bk, s, 0, 0, 0);
      }
      const float es = SCALE * __expf(av - cmax);
      const bool diag = (st == diagST);
#pragma unroll
      for (int reg = 0; reg < 16; ++reg) {
        const int rowl = (reg & 3) + 8 * (reg >> 2) + 4 * hh;
        float pv = s[reg] * es;
        if (diag && (keyg > qrow0 + rowl)) pv = 0.f;
        rs[reg] += pv;
        Plw[rowl * 32 + ((plc ^ (rowl & 3)) * 8) + pl7] = f2bfu(pv);
      }
#pragma unroll
      for (int k2 = 0; k2 < 2; ++k2) {
        const int cb = 2 * k2 + hh;
        const bf16x8 pa = ldsFrag(Plw + l32 * 32 + ((cb ^ (l32 & 3)) * 8));
        const int kb = half * 4 + 2 * k2 + hh;
#pragma unroll
        for (int nt = 0; nt < 4; ++nt) {
          const int n = nt * 32 + l32;
          const bf16x8 bv = ldsFrag(Vb_ + n * 64 + ((kb ^ (n & 7)) * 8));
          oa[nt] = __builtin_amdgcn_mfma_f32_32x32x16_bf16(pa, bv, oa[nt], 0, 0, 0);
        }
      }
    }
    if (st + 1 < nST) stage_commit(b ^ 1);
    __syncthreads();
  }

  // ---- combine key-halves + epilogue ----
  float* osh = (float*)SM;               // 4 combos x 32x128 f32 (64 KB)
  float* rsh = (float*)(SM + 65536);     // 4 combos x 32 f32
  const int combo = qsel * 2 + strip;

#pragma unroll
  for (int reg = 0; reg < 16; ++reg) {
    float x = rs[reg];
#pragma unroll
    for (int off = 1; off < 32; off <<= 1) x += __shfl_xor(x, off, 64);
    rs[reg] = x;
  }

  if (half == 1) {
#pragma unroll
    for (int nt = 0; nt < 4; ++nt)
#pragma unroll
      for (int reg = 0; reg < 16; ++reg) {
        const int rowl = (reg & 3) + 8 * (reg >> 2) + 4 * hh;
        osh[combo * 4096 + rowl * 128 + nt * 32 + l32] = oa[nt][reg];
      }
    if (l32 == 0) {
#pragma unroll
      for (int reg = 0; reg < 16; ++reg) {
        const int rowl = (reg & 3) + 8 * (reg >> 2) + 4 * hh;
        rsh[combo * 32 + rowl] = rs[reg];
      }
    }
  }
  __syncthreads();
  if (half == 0) {
    float inv[16];
#pragma unroll
    for (int reg = 0; reg < 16; ++reg) {
      const int rowl = (reg & 3) + 8 * (reg >> 2) + 4 * hh;
      const float rtot = rs[reg] + rsh[combo * 32 + rowl];
      const float fcv = fcg[goff + qrow0 + rowl];
      inv[reg] = 1.f / fmaxf(fabsf(rtot), __expf(-(cmax + fcv)));
    }
    float* op = out + hoff;
#pragma unroll
    for (int nt = 0; nt < 4; ++nt)
#pragma unroll
      for (int reg = 0; reg < 16; ++reg) {
        const int rowl = (reg & 3) + 8 * (reg >> 2) + 4 * hh;
        const float ov = oa[nt][reg] + osh[combo * 4096 + rowl * 128 + nt * 32 + l32];
        op[(size_t)(qrow0 + rowl) * DHEAD + nt * 32 + l32] = ov * inv[reg];
      }
  }
}

// ---------------------------------------------------------------------------
extern "C" void kernel_launch(void* const* d_in, const int* in_sizes, int n_in,
                              void* d_out, int out_size, void* d_ws, size_t ws_size,
                              hipStream_t stream) {
  const float* q  = (const float*)d_in[0];
  const float* k  = (const float*)d_in[1];
  const float* v  = (const float*)d_in[2];
  const float* ig = (const float*)d_in[3];
  const float* fg = (const float*)d_in[4];

  const size_t gate_bytes = (size_t)3 * NBH * T_SEQ * sizeof(float);
  const size_t kv_elems   = (size_t)NBH * T_SEQ * DHEAD;
  const bool fast = ws_size >= gate_bytes + 2 * kv_elems * sizeof(u16);

  float* a_ws  = (float*)d_ws;
  float* c_ws  = a_ws + NBH * T_SEQ;
  float* fc_ws = c_ws + NBH * T_SEQ;
  u16* kbf  = (u16*)((char*)d_ws + gate_bytes);
  u16* vtbf = kbf + kv_elems;

  gate_scan_kernel<<<dim3(NBH), dim3(256), 0, stream>>>(ig, fg, a_ws, c_ws, fc_ws);
  if (fast) {
    cvt_k_kernel<<<dim3((unsigned)(kv_elems / 1024)), dim3(256), 0, stream>>>(k, kbf);
    cvt_vt_kernel<<<dim3(T_SEQ / 64, NBH), dim3(256), 0, stream>>>(v, vtbf);
    mlstm_fwd_kernel<true><<<dim3(256), dim3(512), 0, stream>>>(
        q, k, v, kbf, vtbf, a_ws, c_ws, fc_ws, (float*)d_out);
  } else {
    mlstm_fwd_kernel<false><<<dim3(256), dim3(512), 0, stream>>>(
        q, k, v, kbf, vtbf, a_ws, c_ws, fc_ws, (float*)d_out);
  }
}